// Round 18
// baseline (9473.299 us; speedup 1.0000x reference)
//
#include <hip/hip_runtime.h>

typedef unsigned long long ull;
typedef unsigned int uint;
typedef unsigned short ushort;
typedef float  f32x2 __attribute__((ext_vector_type(2)));
typedef float  f32x4 __attribute__((ext_vector_type(4)));
typedef short  s16x8 __attribute__((ext_vector_type(8)));
typedef uint   u32x4 __attribute__((ext_vector_type(4)));

constexpr int BATCH = 256;
constexpr int TT    = 1024;
constexpr int HD    = 512;
constexpr int A_SZ    = 16 * HD * 2;       // 16384 B per A split (bf16 [16][512], all rows real)
constexpr int SCR_OFF = 3 * A_SZ;          // 49152: K-reduce scratch (2 nt x 64 lanes x 16B)
constexpr int LDS_USED  = SCR_OFF + 2048;  // 51200 touched
constexpr int LDS_BYTES = 83968;           // >81920: pins 1 wg/CU
constexpr uint SENT = 0x80000000u;         // -0.0f, unreachable by sanitized relu out

__device__ __forceinline__ ushort f2bf(float f) {
    uint u = __float_as_uint(f);
    return (ushort)((u + 0x7fffu + ((u >> 16) & 1u)) >> 16);
}
__device__ __forceinline__ float bf2f(ushort b) {
    return __uint_as_float((uint)b << 16);
}
__device__ __forceinline__ void split3(float v, ushort& h, ushort& m, ushort& l) {
    h = f2bf(v);
    float r1 = v - bf2f(h);
    m = f2bf(r1);
    float r2 = r1 - bf2f(m);
    l = f2bf(r2);
}
// R7-validated swizzle within a [rows][512] bf16 region (writer/reader consistent)
__device__ __forceinline__ uint swz(uint r, uint k) {
    return (r * 1024u + k * 2u) ^ (((r ^ (k >> 6)) & 7u) << 4);
}
// lgkm-only barrier: orders LDS across waves WITHOUT draining vmcnt
__device__ __forceinline__ void bar_lds() {
    asm volatile("s_waitcnt lgkmcnt(0)" ::: "memory");
    __builtin_amdgcn_s_barrier();
}

__global__ void __launch_bounds__(256, 1)
fill_kernel(uint* __restrict__ out)   // arm out[1..1024] with sentinel
{
    const size_t n = (size_t)TT * BATCH * HD / 4;
    uint* base = out + (size_t)BATCH * HD;
    u32x4 s = {SENT, SENT, SENT, SENT};
    for (size_t j = (size_t)blockIdx.x * 256 + threadIdx.x; j < n;
         j += (size_t)gridDim.x * 256)
        *(u32x4*)(base + j * 4) = s;
}

__global__ void __launch_bounds__(256, 1)
init_kernel(float* __restrict__ out)  // out[0] = h0 pattern
{
    int base = (blockIdx.x * 256 + threadIdx.x) * 4;
    int k = base & 511;
    f32x4 v = {0.f, 0.f, 0.f, 0.f};
    if (k == 0 || k == 256) v.x = 1.f;
    *(f32x4*)(out + base) = v;
}

__global__ void __launch_bounds__(256, 1)
rnn_m16p_kernel(const float* __restrict__ x, const float* __restrict__ Wh,
                const float* __restrict__ Wx, const float* __restrict__ bx,
                float* __restrict__ out)
{
    extern __shared__ char lds[];
    char* Ah = lds;
    char* Am = lds + A_SZ;
    char* Al = lds + 2 * A_SZ;

    const int tid  = threadIdx.x;
    const int wid  = blockIdx.x;
    const int rg   = wid & 15;        // row group: rows rg*16..+15
    const int cg   = wid >> 4;        // col group: cols cg*32..+31
    const int lane = tid & 63;
    const int wv   = tid >> 6;
    const int nt   = wv >> 1;         // N-tile (16 cols) 0..1
    const int kq   = wv & 1;          // K-quarter selector within each phase
    const int m    = lane & 15;       // frag row (A) / col (B) — ALL 16 rows real
    const int koct = lane >> 4;

    // ---- prologue: zero A planes + scr; h0 ones (16 rows) ----
    for (int i = tid; i < LDS_USED / 4; i += 256) ((uint*)lds)[i] = 0u;
    __syncthreads();
    if (tid < 32) {
        uint r = (uint)(tid & 15), k = (uint)(tid >> 4) * 256;
        *(uint*)(Ah + swz(r, k)) = 0x3F80u;   // bf16 1.0 at k, 0 at k+1
    }

    // ---- B: all 3 splits in regs (96 VGPR); slot s: s<4 -> phase0 kt=kq*4+s,
    //      s>=4 -> phase1 kt=8+kq*4+(s-4). All indices compile-time in use sites. ----
    s16x8 bh[8], bm[8], bl[8];
    const int colW = cg * 32 + nt * 16 + m;
    {
        const float* wrow = Wh + (size_t)colW * HD;
        #pragma unroll
        for (int s = 0; s < 8; ++s) {
            const int kt_g = (s < 4) ? (kq * 4 + s) : (8 + kq * 4 + (s - 4));
            const float* p = wrow + kt_g * 32 + koct * 8;
            f32x4 v0 = *(const f32x4*)p;
            f32x4 v1 = *(const f32x4*)(p + 4);
            float vv[8] = {v0.x, v0.y, v0.z, v0.w, v1.x, v1.y, v1.z, v1.w};
            s16x8 th, tm, tl;
            #pragma unroll
            for (int q = 0; q < 8; ++q) {
                ushort hh, mm, ll; split3(vv[q], hh, mm, ll);
                th[q] = (short)hh; tm[q] = (short)mm; tl[q] = (short)ll;
            }
            bh[s] = th; bm[s] = tm; bl[s] = tl;
        }
    }

    const f32x2 wxv = *(const f32x2*)(Wx + colW * 2);
    const float bq  = bx[colW];
    const bool doEp = (kq == 0);                   // kq0 waves reduce + store
    const int  r0   = koct * 4;                    // C/D: row = koct*4 + reg (m89)

    // ---- exchange mapping: thread = (row = tid>>4, 16-col strip (tid&15)*16) ----
    const int exr = tid >> 4;                      // 0..15
    const int cbl = (tid & 15) * 16;               // low-half col base (8 ull)
    const size_t rowoff = (size_t)(rg * 16 + exr) * HD + cbl;

    ull vhi[8];                                    // polls for cols 256..511, 1 iter ahead

    __syncthreads();   // A (h0) ready

    for (int t = 0; t < TT; ++t) {
        f32x2 xr[4];
        if (doEp) {
            #pragma unroll
            for (int r = 0; r < 4; ++r)
                xr[r] = *(const f32x2*)(x + ((size_t)(rg * 16 + r0 + r) * TT + t) * 2);
        }

        // ---- phase0: A_low, slots 0..3 (kt = kq*4+j) ----
        f32x4 a0 = {0,0,0,0}, a1 = {0,0,0,0}, a2 = {0,0,0,0}, a3 = {0,0,0,0};
        #pragma unroll
        for (int j = 0; j < 4; ++j) {
            const uint kl = (uint)((kq * 4 + j) * 32 + koct * 8);
            const uint ao = swz((uint)m, kl);
            s16x8 fh = *(const s16x8*)(Ah + ao);
            s16x8 fm = *(const s16x8*)(Am + ao);
            s16x8 fl = *(const s16x8*)(Al + ao);
            a0 = __builtin_amdgcn_mfma_f32_16x16x32_bf16(fh, bh[j], a0, 0, 0, 0);
            a1 = __builtin_amdgcn_mfma_f32_16x16x32_bf16(fh, bm[j], a1, 0, 0, 0);
            a2 = __builtin_amdgcn_mfma_f32_16x16x32_bf16(fm, bh[j], a2, 0, 0, 0);
            a3 = __builtin_amdgcn_mfma_f32_16x16x32_bf16(fm, bm[j], a3, 0, 0, 0);
            a1 = __builtin_amdgcn_mfma_f32_16x16x32_bf16(fh, bl[j], a1, 0, 0, 0);
            a2 = __builtin_amdgcn_mfma_f32_16x16x32_bf16(fl, bh[j], a2, 0, 0, 0);
        }

        // ---- waitA: high cols of h_t (polls in flight since last iter; hidden by phase0) ----
        if (t > 0) {
            const float* sh = out + (size_t)t * BATCH * HD + rowoff + 256;
            for (;;) {
                bool ok = true;
                #pragma unroll
                for (int i = 0; i < 8; ++i)
                    if ((uint)vhi[i] == SENT || (uint)(vhi[i] >> 32) == SENT) ok = false;
                if (ok) break;
                __builtin_amdgcn_s_sleep(1);
                #pragma unroll
                for (int i = 0; i < 8; ++i)
                    vhi[i] = __hip_atomic_load((const ull*)(sh + 2 * i),
                                               __ATOMIC_RELAXED, __HIP_MEMORY_SCOPE_AGENT);
            }
            #pragma unroll
            for (int i = 0; i < 8; ++i) {
                union { ull u; f32x2 f; } cu; cu.u = vhi[i];
                ushort h0, m0, l0, h1, m1, l1;
                split3(cu.f.x, h0, m0, l0);
                split3(cu.f.y, h1, m1, l1);
                uint off = swz((uint)exr, (uint)(256 + cbl + 2 * i));
                *(uint*)(Ah + off) = (uint)h0 | ((uint)h1 << 16);
                *(uint*)(Am + off) = (uint)m0 | ((uint)m1 << 16);
                *(uint*)(Al + off) = (uint)l0 | ((uint)l1 << 16);
            }
        }
        bar_lds();   // B3: A_high(t) ready

        // ---- phase1: A_high, slots 4..7 (kt = 8+kq*4+j) ----
        #pragma unroll
        for (int j = 0; j < 4; ++j) {
            const uint kl = (uint)((8 + kq * 4 + j) * 32 + koct * 8);
            const uint ao = swz((uint)m, kl);
            s16x8 fh = *(const s16x8*)(Ah + ao);
            s16x8 fm = *(const s16x8*)(Am + ao);
            s16x8 fl = *(const s16x8*)(Al + ao);
            a0 = __builtin_amdgcn_mfma_f32_16x16x32_bf16(fh, bh[4 + j], a0, 0, 0, 0);
            a1 = __builtin_amdgcn_mfma_f32_16x16x32_bf16(fh, bm[4 + j], a1, 0, 0, 0);
            a2 = __builtin_amdgcn_mfma_f32_16x16x32_bf16(fm, bh[4 + j], a2, 0, 0, 0);
            a3 = __builtin_amdgcn_mfma_f32_16x16x32_bf16(fm, bm[4 + j], a3, 0, 0, 0);
            a1 = __builtin_amdgcn_mfma_f32_16x16x32_bf16(fh, bl[4 + j], a1, 0, 0, 0);
            a2 = __builtin_amdgcn_mfma_f32_16x16x32_bf16(fl, bh[4 + j], a2, 0, 0, 0);
        }
        f32x4 acc = (a0 + a1) + (a2 + a3);

        // ---- K-reduce staging + early poll issue ----
        float* scr = (float*)(lds + SCR_OFF);
        if (!doEp) *(f32x4*)(scr + ((size_t)nt * 64 + lane) * 4) = acc;   // kq1 partials
        ull vlo[8];
        const float* sl = out + (size_t)(t + 1) * BATCH * HD + rowoff;    // slab t+1
        if (t + 1 < TT) {
            #pragma unroll
            for (int i = 0; i < 8; ++i)
                vlo[i] = __hip_atomic_load((const ull*)(sl + 2 * i),
                                           __ATOMIC_RELAXED, __HIP_MEMORY_SCOPE_AGENT);
        }
        bar_lds();   // B1: partials ready; all A(t) reads done

        // ---- reduce + epilogue + stores (kq0 waves) ----
        if (doEp) {
            acc += *(const f32x4*)(scr + ((size_t)nt * 64 + lane) * 4);
            uint u0, u1, u2, u3;
            {
                float y0 = fmaxf(acc[0] + fmaf(xr[0].x, wxv.x, fmaf(xr[0].y, wxv.y, bq)), 0.f);
                float y1 = fmaxf(acc[1] + fmaf(xr[1].x, wxv.x, fmaf(xr[1].y, wxv.y, bq)), 0.f);
                float y2 = fmaxf(acc[2] + fmaf(xr[2].x, wxv.x, fmaf(xr[2].y, wxv.y, bq)), 0.f);
                float y3 = fmaxf(acc[3] + fmaf(xr[3].x, wxv.x, fmaf(xr[3].y, wxv.y, bq)), 0.f);
                u0 = __float_as_uint(y0); if (u0 == SENT) u0 = 0u;
                u1 = __float_as_uint(y1); if (u1 == SENT) u1 = 0u;
                u2 = __float_as_uint(y2); if (u2 == SENT) u2 = 0u;
                u3 = __float_as_uint(y3); if (u3 == SENT) u3 = 0u;
            }
            uint q0 = (uint)__shfl_xor((int)u0, 1);
            uint q1 = (uint)__shfl_xor((int)u1, 1);
            uint q2 = (uint)__shfl_xor((int)u2, 1);
            uint q3 = (uint)__shfl_xor((int)u3, 1);
            if (!(lane & 1)) {
                float* obase = out + (size_t)(t + 1) * BATCH * HD;
                const int rb = rg * 16 + r0;
                __hip_atomic_store((ull*)(obase + (size_t)(rb + 0) * HD + colW),
                                   (ull)u0 | ((ull)q0 << 32), __ATOMIC_RELAXED, __HIP_MEMORY_SCOPE_AGENT);
                __hip_atomic_store((ull*)(obase + (size_t)(rb + 1) * HD + colW),
                                   (ull)u1 | ((ull)q1 << 32), __ATOMIC_RELAXED, __HIP_MEMORY_SCOPE_AGENT);
                __hip_atomic_store((ull*)(obase + (size_t)(rb + 2) * HD + colW),
                                   (ull)u2 | ((ull)q2 << 32), __ATOMIC_RELAXED, __HIP_MEMORY_SCOPE_AGENT);
                __hip_atomic_store((ull*)(obase + (size_t)(rb + 3) * HD + colW),
                                   (ull)u3 | ((ull)q3 << 32), __ATOMIC_RELAXED, __HIP_MEMORY_SCOPE_AGENT);
            }
        }

        if (t + 1 < TT) {
            // ---- wait low cols of h_{t+1}; split -> A_low ----
            for (;;) {
                bool ok = true;
                #pragma unroll
                for (int i = 0; i < 8; ++i)
                    if ((uint)vlo[i] == SENT || (uint)(vlo[i] >> 32) == SENT) ok = false;
                if (ok) break;
                __builtin_amdgcn_s_sleep(1);
                #pragma unroll
                for (int i = 0; i < 8; ++i)
                    vlo[i] = __hip_atomic_load((const ull*)(sl + 2 * i),
                                               __ATOMIC_RELAXED, __HIP_MEMORY_SCOPE_AGENT);
            }
            #pragma unroll
            for (int i = 0; i < 8; ++i) {
                union { ull u; f32x2 f; } cu; cu.u = vlo[i];
                ushort h0, m0, l0, h1, m1, l1;
                split3(cu.f.x, h0, m0, l0);
                split3(cu.f.y, h1, m1, l1);
                uint off = swz((uint)exr, (uint)(cbl + 2 * i));
                *(uint*)(Ah + off) = (uint)h0 | ((uint)h1 << 16);
                *(uint*)(Am + off) = (uint)m0 | ((uint)m1 << 16);
                *(uint*)(Al + off) = (uint)l0 | ((uint)l1 << 16);
            }
            // issue polls for high cols (checked next iter, hidden under phase0)
            #pragma unroll
            for (int i = 0; i < 8; ++i)
                vhi[i] = __hip_atomic_load((const ull*)(sl + 256 + 2 * i),
                                           __ATOMIC_RELAXED, __HIP_MEMORY_SCOPE_AGENT);
            bar_lds();   // B2: A_low(t+1) ready
        }
    }
}

extern "C" void kernel_launch(void* const* d_in, const int* in_sizes, int n_in,
                              void* d_out, int out_size, void* d_ws, size_t ws_size,
                              hipStream_t stream) {
    const float* x  = (const float*)d_in[0];
    const float* Wh = (const float*)d_in[1];
    const float* Wx = (const float*)d_in[2];
    const float* bx = (const float*)d_in[3];
    float* out = (float*)d_out;

    (void)hipFuncSetAttribute((const void*)rnn_m16p_kernel,
                              hipFuncAttributeMaxDynamicSharedMemorySize, LDS_BYTES);

    fill_kernel<<<dim3(4096), dim3(256), 0, stream>>>((uint*)out);
    init_kernel<<<dim3(BATCH * HD / 4 / 256), dim3(256), 0, stream>>>(out);

    void* args[] = { (void*)&x, (void*)&Wh, (void*)&Wx, (void*)&bx, (void*)&out };
    hipError_t ce = hipLaunchCooperativeKernel((const void*)rnn_m16p_kernel,
                                               dim3(256), dim3(256), args, LDS_BYTES, stream);
    if (ce != hipSuccess) {
        rnn_m16p_kernel<<<dim3(256), dim3(256), LDS_BYTES, stream>>>(x, Wh, Wx, bx, out);
    }
}

// Round 19
// 2810.226 us; speedup vs baseline: 3.3710x; 3.3710x over previous
//
#include <hip/hip_runtime.h>

typedef unsigned long long ull;
typedef unsigned int uint;
typedef unsigned short ushort;
typedef float  f32x2 __attribute__((ext_vector_type(2)));
typedef float  f32x4 __attribute__((ext_vector_type(4)));
typedef short  s16x8 __attribute__((ext_vector_type(8)));
typedef uint   u32x4 __attribute__((ext_vector_type(4)));

constexpr int BATCH = 256;
constexpr int TT    = 1024;
constexpr int HD    = 512;
constexpr int A_SZ    = 8 * HD * 2;        // 8192 B per A split (bf16 [8][512])
constexpr int ZB_OFF  = 3 * A_SZ;          // 24576: zero block (padded A rows 8..15)
constexpr int LDS_USED  = ZB_OFF + 256;    // 24832 actually touched
constexpr int LDS_BYTES = 83968;           // >81920: pins 1 wg/CU (capacity)
constexpr uint SENT = 0x80000000u;         // -0.0f, unreachable by sanitized relu out

__device__ __forceinline__ float bf2f(ushort b) {
    return __uint_as_float((uint)b << 16);
}
// EXACT truncation 3-split: v == hi+mid+lo (24 mantissa bits = 8+8+8 captured
// exactly; r1 = v-hi and r2 = r1-mid are exact fp32 subtractions; r3 == 0).
// Cheaper than RNE split (no bias-add chains) AND numerically exact.
__device__ __forceinline__ void split3(float v, ushort& h, ushort& m, ushort& l) {
    uint u = __float_as_uint(v);
    h = (ushort)(u >> 16);
    float r1 = v - bf2f(h);
    m = (ushort)(__float_as_uint(r1) >> 16);
    float r2 = r1 - bf2f(m);
    l = (ushort)(__float_as_uint(r2) >> 16);
}
// R7-validated swizzle within a [rows][512] bf16 region (writer/reader consistent)
__device__ __forceinline__ uint swz(uint r, uint k) {
    return (r * 1024u + k * 2u) ^ (((r ^ (k >> 6)) & 7u) << 4);
}
// lgkm-only barrier: orders LDS across waves WITHOUT draining vmcnt (no store-ack wait)
__device__ __forceinline__ void bar_lds() {
    asm volatile("s_waitcnt lgkmcnt(0)" ::: "memory");
    __builtin_amdgcn_s_barrier();
}

__global__ void __launch_bounds__(256, 1)
fill_kernel(uint* __restrict__ out)   // arm out[1..1024] with sentinel
{
    const size_t n = (size_t)TT * BATCH * HD / 4;
    uint* base = out + (size_t)BATCH * HD;
    u32x4 s = {SENT, SENT, SENT, SENT};
    for (size_t j = (size_t)blockIdx.x * 256 + threadIdx.x; j < n;
         j += (size_t)gridDim.x * 256)
        *(u32x4*)(base + j * 4) = s;
}

__global__ void __launch_bounds__(256, 1)
init_kernel(float* __restrict__ out)  // out[0] = h0 pattern
{
    int base = (blockIdx.x * 256 + threadIdx.x) * 4;
    int k = base & 511;
    f32x4 v = {0.f, 0.f, 0.f, 0.f};
    if (k == 0 || k == 256) v.x = 1.f;
    *(f32x4*)(out + base) = v;
}

__global__ void __launch_bounds__(256, 1)
rnn_pipe3_kernel(const float* __restrict__ x, const float* __restrict__ Wh,
                 const float* __restrict__ Wx, const float* __restrict__ bx,
                 float* __restrict__ out)
{
    extern __shared__ char lds[];
    char* Ah  = lds;
    char* Am  = lds + A_SZ;
    char* Al  = lds + 2 * A_SZ;
    char* ZB  = lds + ZB_OFF;

    const int tid  = threadIdx.x;
    const int wid  = blockIdx.x;
    const int gb   = wid & 31;        // batch group (8 rows)
    const int gh   = wid >> 5;        // h-slice group (64 outs)
    const int lane = tid & 63;
    const int wv   = tid >> 6;        // wave = N-tile (16 outs)
    const int m    = lane & 15;       // frag row (A) / col (B)
    const int koct = lane >> 4;
    const bool mhi = (m >= 8);        // padded A rows -> zero block

    // ---- prologue: zero A region + ZB; h0 ones (both halves) ----
    for (int i = tid; i < LDS_USED / 4; i += 256) ((uint*)lds)[i] = 0u;
    __syncthreads();
    if (tid < 16) {
        uint r = (uint)(tid & 7), k = (uint)((tid >> 3) * 256);
        *(uint*)(Ah + swz(r, k)) = 0x3F80u;   // bf16 1.0 at k (k=0 -> A_low, k=256 -> A_high)
    }

    // ---- B: ALL 3 splits in registers (192 VGPR for B) ----
    s16x8 bh[16], bm[16], bl[16];
    {
        const int ol = wv * 16 + m;
        const float* wrow = Wh + (size_t)(gh * 64 + ol) * HD;
        #pragma unroll
        for (int kt = 0; kt < 16; ++kt) {
            const float* p = wrow + kt * 32 + koct * 8;
            f32x4 v0 = *(const f32x4*)p;
            f32x4 v1 = *(const f32x4*)(p + 4);
            float vv[8] = {v0.x, v0.y, v0.z, v0.w, v1.x, v1.y, v1.z, v1.w};
            s16x8 th, tm, tl;
            #pragma unroll
            for (int j = 0; j < 8; ++j) {
                ushort hh, mm, ll; split3(vv[j], hh, mm, ll);
                th[j] = (short)hh; tm[j] = (short)mm; tl[j] = (short)ll;
            }
            bh[kt] = th; bm[kt] = tm; bl[kt] = tl;
        }
    }

    const int  col  = gh * 64 + wv * 16 + m;
    const f32x2 wxv = *(const f32x2*)(Wx + col * 2);
    const float bq  = bx[col];
    const bool doEp = (lane < 32);
    const int  r0   = koct * 4;                    // C/D: row = koct*4 + reg (m89)

    const int exr = tid >> 5;
    const int ccx = (tid & 31) * 2;
    const size_t rowoff = (size_t)(gb * 8 + exr) * HD + ccx;   // offset within a t-slab

    ull vhi[4];                        // polls for chunks 4..7, issued one iter ahead

    __syncthreads();   // A tiles (h0) ready

    for (int t = 0; t < TT; ++t) {
        f32x2 xr[4];
        if (doEp) {
            #pragma unroll
            for (int r = 0; r < 4; ++r)
                xr[r] = *(const f32x2*)(x + ((size_t)(gb * 8 + r0 + r) * TT + t) * 2);
        }

        // ---- phase0: kt 0..7 (A_low) ----
        f32x4 a0 = {0,0,0,0}, a1 = {0,0,0,0}, a2 = {0,0,0,0}, a3 = {0,0,0,0};
        #pragma unroll
        for (int kt = 0; kt < 8; ++kt) {
            const uint kl = (uint)(kt * 32 + koct * 8);
            const uint ao = swz((uint)m, kl);
            s16x8 fh = *(const s16x8*)(mhi ? ZB : (Ah + ao));
            s16x8 fm = *(const s16x8*)(mhi ? ZB : (Am + ao));
            s16x8 fl = *(const s16x8*)(mhi ? ZB : (Al + ao));
            a0 = __builtin_amdgcn_mfma_f32_16x16x32_bf16(fh, bh[kt], a0, 0, 0, 0);
            a1 = __builtin_amdgcn_mfma_f32_16x16x32_bf16(fh, bm[kt], a1, 0, 0, 0);
            a2 = __builtin_amdgcn_mfma_f32_16x16x32_bf16(fm, bh[kt], a2, 0, 0, 0);
            a3 = __builtin_amdgcn_mfma_f32_16x16x32_bf16(fm, bm[kt], a3, 0, 0, 0);
            a1 = __builtin_amdgcn_mfma_f32_16x16x32_bf16(fh, bl[kt], a1, 0, 0, 0);
            a2 = __builtin_amdgcn_mfma_f32_16x16x32_bf16(fl, bh[kt], a2, 0, 0, 0);
        }

        // ---- wait + split chunks 4..7 of h_t (polls issued last iter; t=0 staged) ----
        if (t > 0) {
            const float* sh = out + (size_t)t * BATCH * HD + rowoff;
            for (;;) {
                bool ok = true;
                #pragma unroll
                for (int p = 0; p < 4; ++p)
                    if ((uint)vhi[p] == SENT || (uint)(vhi[p] >> 32) == SENT) ok = false;
                if (ok) break;
                __builtin_amdgcn_s_sleep(1);
                #pragma unroll
                for (int p = 0; p < 4; ++p)
                    vhi[p] = __hip_atomic_load((const ull*)(sh + (p + 4) * 64),
                                               __ATOMIC_RELAXED, __HIP_MEMORY_SCOPE_AGENT);
            }
            #pragma unroll
            for (int p = 0; p < 4; ++p) {
                union { ull u; f32x2 f; } cu; cu.u = vhi[p];
                ushort h0, m0, l0, h1, m1, l1;
                split3(cu.f.x, h0, m0, l0);
                split3(cu.f.y, h1, m1, l1);
                uint off = swz((uint)exr, (uint)((p + 4) * 64 + ccx));
                *(uint*)(Ah + off) = (uint)h0 | ((uint)h1 << 16);
                *(uint*)(Am + off) = (uint)m0 | ((uint)m1 << 16);
                *(uint*)(Al + off) = (uint)l0 | ((uint)l1 << 16);
            }
        }
        bar_lds();   // B3: A_high(t) ready for all waves

        // ---- phase1: kt 8..15 (A_high) ----
        #pragma unroll
        for (int kt = 8; kt < 16; ++kt) {
            const uint kl = (uint)(kt * 32 + koct * 8);
            const uint ao = swz((uint)m, kl);
            s16x8 fh = *(const s16x8*)(mhi ? ZB : (Ah + ao));
            s16x8 fm = *(const s16x8*)(mhi ? ZB : (Am + ao));
            s16x8 fl = *(const s16x8*)(mhi ? ZB : (Al + ao));
            a0 = __builtin_amdgcn_mfma_f32_16x16x32_bf16(fh, bh[kt], a0, 0, 0, 0);
            a1 = __builtin_amdgcn_mfma_f32_16x16x32_bf16(fh, bm[kt], a1, 0, 0, 0);
            a2 = __builtin_amdgcn_mfma_f32_16x16x32_bf16(fm, bh[kt], a2, 0, 0, 0);
            a3 = __builtin_amdgcn_mfma_f32_16x16x32_bf16(fm, bm[kt], a3, 0, 0, 0);
            a1 = __builtin_amdgcn_mfma_f32_16x16x32_bf16(fh, bl[kt], a1, 0, 0, 0);
            a2 = __builtin_amdgcn_mfma_f32_16x16x32_bf16(fl, bh[kt], a2, 0, 0, 0);
        }
        f32x4 acc = (a0 + a1) + (a2 + a3);

        // ---- epilogue: relu, sanitize, pair cols, 8B stores (fire-and-forget) ----
        uint u0 = 0, u1 = 0, u2 = 0, u3 = 0;
        if (doEp) {
            float y0 = fmaxf(acc[0] + fmaf(xr[0].x, wxv.x, fmaf(xr[0].y, wxv.y, bq)), 0.f);
            float y1 = fmaxf(acc[1] + fmaf(xr[1].x, wxv.x, fmaf(xr[1].y, wxv.y, bq)), 0.f);
            float y2 = fmaxf(acc[2] + fmaf(xr[2].x, wxv.x, fmaf(xr[2].y, wxv.y, bq)), 0.f);
            float y3 = fmaxf(acc[3] + fmaf(xr[3].x, wxv.x, fmaf(xr[3].y, wxv.y, bq)), 0.f);
            u0 = __float_as_uint(y0); if (u0 == SENT) u0 = 0u;
            u1 = __float_as_uint(y1); if (u1 == SENT) u1 = 0u;
            u2 = __float_as_uint(y2); if (u2 == SENT) u2 = 0u;
            u3 = __float_as_uint(y3); if (u3 == SENT) u3 = 0u;
        }
        uint p0 = (uint)__shfl_xor((int)u0, 1);
        uint p1 = (uint)__shfl_xor((int)u1, 1);
        uint p2 = (uint)__shfl_xor((int)u2, 1);
        uint p3 = (uint)__shfl_xor((int)u3, 1);
        if (doEp && !(lane & 1)) {
            float* obase = out + (size_t)(t + 1) * BATCH * HD;
            __hip_atomic_store((ull*)(obase + (size_t)(gb * 8 + r0 + 0) * HD + col),
                               (ull)u0 | ((ull)p0 << 32), __ATOMIC_RELAXED, __HIP_MEMORY_SCOPE_AGENT);
            __hip_atomic_store((ull*)(obase + (size_t)(gb * 8 + r0 + 1) * HD + col),
                               (ull)u1 | ((ull)p1 << 32), __ATOMIC_RELAXED, __HIP_MEMORY_SCOPE_AGENT);
            __hip_atomic_store((ull*)(obase + (size_t)(gb * 8 + r0 + 2) * HD + col),
                               (ull)u2 | ((ull)p2 << 32), __ATOMIC_RELAXED, __HIP_MEMORY_SCOPE_AGENT);
            __hip_atomic_store((ull*)(obase + (size_t)(gb * 8 + r0 + 3) * HD + col),
                               (ull)u3 | ((ull)p3 << 32), __ATOMIC_RELAXED, __HIP_MEMORY_SCOPE_AGENT);
        }

        if (t + 1 < TT) {
            const float* sl = out + (size_t)(t + 1) * BATCH * HD + rowoff;
            // issue polls for chunks 0..3 immediately (overlaps barrier below)
            ull vlo[4];
            #pragma unroll
            for (int p = 0; p < 4; ++p)
                vlo[p] = __hip_atomic_load((const ull*)(sl + p * 64),
                                           __ATOMIC_RELAXED, __HIP_MEMORY_SCOPE_AGENT);
            bar_lds();   // B1: all A(t) reads done (phase1 complete everywhere)

            for (;;) {
                bool ok = true;
                #pragma unroll
                for (int p = 0; p < 4; ++p)
                    if ((uint)vlo[p] == SENT || (uint)(vlo[p] >> 32) == SENT) ok = false;
                if (ok) break;
                __builtin_amdgcn_s_sleep(1);
                #pragma unroll
                for (int p = 0; p < 4; ++p)
                    vlo[p] = __hip_atomic_load((const ull*)(sl + p * 64),
                                               __ATOMIC_RELAXED, __HIP_MEMORY_SCOPE_AGENT);
            }
            #pragma unroll
            for (int p = 0; p < 4; ++p) {
                union { ull u; f32x2 f; } cu; cu.u = vlo[p];
                ushort h0, m0, l0, h1, m1, l1;
                split3(cu.f.x, h0, m0, l0);
                split3(cu.f.y, h1, m1, l1);
                uint off = swz((uint)exr, (uint)(p * 64 + ccx));
                *(uint*)(Ah + off) = (uint)h0 | ((uint)h1 << 16);
                *(uint*)(Am + off) = (uint)m0 | ((uint)m1 << 16);
                *(uint*)(Al + off) = (uint)l0 | ((uint)l1 << 16);
            }
            // issue polls for chunks 4..7 (checked next iter, hidden under phase0)
            #pragma unroll
            for (int p = 0; p < 4; ++p)
                vhi[p] = __hip_atomic_load((const ull*)(sl + (p + 4) * 64),
                                           __ATOMIC_RELAXED, __HIP_MEMORY_SCOPE_AGENT);
            bar_lds();   // B2: A_low(t+1) ready for all waves
        }
    }
}

extern "C" void kernel_launch(void* const* d_in, const int* in_sizes, int n_in,
                              void* d_out, int out_size, void* d_ws, size_t ws_size,
                              hipStream_t stream) {
    const float* x  = (const float*)d_in[0];
    const float* Wh = (const float*)d_in[1];
    const float* Wx = (const float*)d_in[2];
    const float* bx = (const float*)d_in[3];
    float* out = (float*)d_out;

    (void)hipFuncSetAttribute((const void*)rnn_pipe3_kernel,
                              hipFuncAttributeMaxDynamicSharedMemorySize, LDS_BYTES);

    fill_kernel<<<dim3(4096), dim3(256), 0, stream>>>((uint*)out);
    init_kernel<<<dim3(BATCH * HD / 4 / 256), dim3(256), 0, stream>>>(out);

    void* args[] = { (void*)&x, (void*)&Wh, (void*)&Wx, (void*)&bx, (void*)&out };
    hipError_t ce = hipLaunchCooperativeKernel((const void*)rnn_pipe3_kernel,
                                               dim3(256), dim3(256), args, LDS_BYTES, stream);
    if (ce != hipSuccess) {
        rnn_pipe3_kernel<<<dim3(256), dim3(256), LDS_BYTES, stream>>>(x, Wh, Wx, bx, out);
    }
}